// Round 2
// baseline (165.813 us; speedup 1.0000x reference)
//
#include <hip/hip_runtime.h>
#include <stdint.h>

// FFEdgeCountingAutoencoder4: two "fuzzy logic" layers.
// Randomness: JAX threefry2x32, PARTITIONABLE counter semantics (default in
// current JAX): for a 32-bit draw at flat index e,
//   (o0, o1) = threefry(key, (e >> 32, e & 0xffffffff));  bits = o0 ^ o1.
// Keys derived host-side:
//   base = key(42) = (0, 42)
//   K_l  = fold_in(base, l) = tf(base, (0, l))          (full 64-bit out)
//   split(K) foldlike: k_op = tf(K,(0,0)), k_edge = tf(K,(0,1))
// Gumbel: u = max(tiny, ((bits>>9)|0x3f800000 as float) - 1);
//         g = -log(-log(u))  (f32 logs; we emulate with f64 log -> f32 round).

__host__ __device__ inline uint32_t rotl32(uint32_t x, uint32_t d) {
  return (x << d) | (x >> (32u - d));
}

__host__ __device__ inline void threefry2x32(uint32_t k0, uint32_t k1,
                                             uint32_t x0, uint32_t x1,
                                             uint32_t* o0, uint32_t* o1) {
  uint32_t ks0 = k0, ks1 = k1, ks2 = k0 ^ k1 ^ 0x1BD11BDAu;
  x0 += ks0; x1 += ks1;
#define TF_R(r) { x0 += x1; x1 = rotl32(x1, r); x1 ^= x0; }
  TF_R(13u) TF_R(15u) TF_R(26u) TF_R(6u)
  x0 += ks1; x1 += ks2 + 1u;
  TF_R(17u) TF_R(29u) TF_R(16u) TF_R(24u)
  x0 += ks2; x1 += ks0 + 2u;
  TF_R(13u) TF_R(15u) TF_R(26u) TF_R(6u)
  x0 += ks0; x1 += ks1 + 3u;
  TF_R(17u) TF_R(29u) TF_R(16u) TF_R(24u)
  x0 += ks1; x1 += ks2 + 4u;
  TF_R(13u) TF_R(15u) TF_R(26u) TF_R(6u)
  x0 += ks2; x1 += ks0 + 5u;
#undef TF_R
  *o0 = x0; *o1 = x1;
}

// 32-bit random word at flat counter e (partitionable scheme): o0 ^ o1.
__device__ __forceinline__ uint32_t rbits32(uint32_t k0, uint32_t k1,
                                            uint32_t e) {
  uint32_t a, b;
  threefry2x32(k0, k1, 0u, e, &a, &b);
  return a ^ b;
}

__device__ __forceinline__ float gumbel_from_u32(uint32_t bits) {
  uint32_t fb = (bits >> 9) | 0x3f800000u;
  float f = __uint_as_float(fb) - 1.0f;          // [0,1), exact
  float u = (f > 0.0f) ? f : 1.17549435e-38f;    // JAX uniform(minval=tiny)
  float l1 = (float)log((double)u);              // correctly-rounded f32 log
  float l2 = (float)log((double)(-l1));
  return -l2;
}

// -------- operator selection: op_idx[o] = argmax_j(otc[o,j] + g[o,j]) --------
__global__ void ops_kernel(const float* __restrict__ otc, int out_f,
                           uint32_t k0, uint32_t k1, int* __restrict__ opidx) {
  int o = blockIdx.x * blockDim.x + threadIdx.x;
  if (o >= out_f) return;
  float v0 = otc[2 * o] + gumbel_from_u32(rbits32(k0, k1, (uint32_t)(2 * o)));
  float v1 = otc[2 * o + 1] +
             gumbel_from_u32(rbits32(k0, k1, (uint32_t)(2 * o + 1)));
  opidx[o] = (v1 > v0) ? 1 : 0;   // argmax, first index wins ties
}

// -------- edge selection: sel[o,i] = argmax_t(etc[o,op,i,t] + g) == 1 --------
template <int IN_F>
__global__ void edges_kernel(const float* __restrict__ etc,
                             const int* __restrict__ opidx,
                             uint32_t k0, uint32_t k1,
                             unsigned long long* __restrict__ selw) {
  int tid = blockIdx.x * blockDim.x + threadIdx.x;  // tid = o*IN_F + i
  int o = tid / IN_F;
  int i = tid & (IN_F - 1);
  int j = opidx[o];
  uint32_t e0 = (uint32_t)(((o * 2 + j) * IN_F + i) * 2);
  float g0 = gumbel_from_u32(rbits32(k0, k1, e0));
  float g1 = gumbel_from_u32(rbits32(k0, k1, e0 + 1u));
  const float* c = etc + (size_t)e0;                // etc flat idx == e0
  bool sel = (c[1] + g1) > (c[0] + g0);
  unsigned long long m = __ballot(sel ? 1 : 0);
  if ((threadIdx.x & 63) == 0) selw[tid >> 6] = m;  // o*(IN_F/64) + i/64
}

// -------- layer forward: out[b,o] = min/max_i (sel ? x[b,i] : neutral) --------
template <int IN_F>
__global__ void forward_kernel(const float* __restrict__ x,
                               const int* __restrict__ opidx,
                               const unsigned long long* __restrict__ selw,
                               float* __restrict__ out, int out_f) {
  __shared__ float xs[IN_F];
  int b = blockIdx.x;
  int o = blockIdx.y * blockDim.x + threadIdx.x;
  for (int i = threadIdx.x; i < IN_F; i += blockDim.x)
    xs[i] = x[(size_t)b * IN_F + i];
  __syncthreads();
  int op = opidx[o];
  const unsigned long long* sw = selw + (size_t)o * (IN_F / 64);
  float acc;
  if (op == 0) {            // T_Norm = min, no-edge contributes 1.0
    acc = 1.0f;
    for (int w = 0; w < IN_F / 64; ++w) {
      unsigned long long m = sw[w];
      const float* xp = xs + w * 64;
#pragma unroll
      for (int k = 0; k < 64; ++k) {
        float v = ((m >> k) & 1ull) ? xp[k] : 1.0f;
        acc = fminf(acc, v);
      }
    }
  } else {                  // T_Conorm = max, no-edge contributes 0.0
    acc = 0.0f;
    for (int w = 0; w < IN_F / 64; ++w) {
      unsigned long long m = sw[w];
      const float* xp = xs + w * 64;
#pragma unroll
      for (int k = 0; k < 64; ++k) {
        float v = ((m >> k) & 1ull) ? xp[k] : 0.0f;
        acc = fmaxf(acc, v);
      }
    }
  }
  out[(size_t)b * out_f + o] = acc;
}

extern "C" void kernel_launch(void* const* d_in, const int* in_sizes, int n_in,
                              void* d_out, int out_size, void* d_ws, size_t ws_size,
                              hipStream_t stream) {
  const float* x    = (const float*)d_in[0];   // [128,1024]
  const float* etc0 = (const float*)d_in[1];   // [512,2,1024,2]
  const float* otc0 = (const float*)d_in[2];   // [512,2]
  const float* etc1 = (const float*)d_in[3];   // [1024,2,512,2]
  const float* otc1 = (const float*)d_in[4];   // [1024,2]
  float* out = (float*)d_out;                  // [128,1024] f32

  // ---- host-side key derivation (pure CPU, graph-capture safe) ----
  uint32_t K0a, K0b, K1a, K1b;
  threefry2x32(0u, 42u, 0u, 0u, &K0a, &K0b);   // fold_in(key(42), 0)
  threefry2x32(0u, 42u, 0u, 1u, &K1a, &K1b);   // fold_in(key(42), 1)
  uint32_t op0k0, op0k1, ed0k0, ed0k1;
  threefry2x32(K0a, K0b, 0u, 0u, &op0k0, &op0k1);  // split(K0)[0] = k_op
  threefry2x32(K0a, K0b, 0u, 1u, &ed0k0, &ed0k1);  // split(K0)[1] = k_edge
  uint32_t op1k0, op1k1, ed1k0, ed1k1;
  threefry2x32(K1a, K1b, 0u, 0u, &op1k0, &op1k1);
  threefry2x32(K1a, K1b, 0u, 1u, &ed1k0, &ed1k1);

  // ---- workspace layout (~392 KB) ----
  char* wsb = (char*)d_ws;
  int* opidx0 = (int*)wsb;                                        // 512 ints
  int* opidx1 = (int*)(wsb + 2048);                               // 1024 ints
  unsigned long long* selw0 = (unsigned long long*)(wsb + 8192);  // 512*16 u64
  unsigned long long* selw1 = (unsigned long long*)(wsb + 8192 + 65536); // 1024*8
  float* h = (float*)(wsb + 8192 + 131072);                       // 128*512 f32

  hipLaunchKernelGGL(ops_kernel, dim3(2), dim3(256), 0, stream,
                     otc0, 512, op0k0, op0k1, opidx0);
  hipLaunchKernelGGL(ops_kernel, dim3(4), dim3(256), 0, stream,
                     otc1, 1024, op1k0, op1k1, opidx1);
  hipLaunchKernelGGL((edges_kernel<1024>), dim3(2048), dim3(256), 0, stream,
                     etc0, opidx0, ed0k0, ed0k1, selw0);
  hipLaunchKernelGGL((edges_kernel<512>), dim3(2048), dim3(256), 0, stream,
                     etc1, opidx1, ed1k0, ed1k1, selw1);
  hipLaunchKernelGGL((forward_kernel<1024>), dim3(128, 2), dim3(256), 0, stream,
                     x, opidx0, selw0, h, 512);
  hipLaunchKernelGGL((forward_kernel<512>), dim3(128, 4), dim3(256), 0, stream,
                     h, opidx1, selw1, out, 1024);
}

// Round 3
// 118.236 us; speedup vs baseline: 1.4024x; 1.4024x over previous
//
#include <hip/hip_runtime.h>
#include <stdint.h>

// FFEdgeCountingAutoencoder4: two "fuzzy logic" layers.
// Randomness: JAX threefry2x32, PARTITIONABLE counter semantics:
//   bits(e) = o0 ^ o1 of threefry(key, (0, e)).   (verified: absmax == 0.0)
// Keys host-side: base=key(42)=(0,42); K_l=tf(base,(0,l));
//   split: k_op=tf(K,(0,0)), k_edge=tf(K,(0,1)).
// Gumbel: u = max(tiny, ((bits>>9)|0x3f800000 as float)-1); g=-log(-log u),
// each log f32-correctly-rounded via f64 log (bit-exact vs reference).

__host__ __device__ inline uint32_t rotl32(uint32_t x, uint32_t d) {
  return (x << d) | (x >> (32u - d));
}

__host__ __device__ inline void threefry2x32(uint32_t k0, uint32_t k1,
                                             uint32_t x0, uint32_t x1,
                                             uint32_t* o0, uint32_t* o1) {
  uint32_t ks0 = k0, ks1 = k1, ks2 = k0 ^ k1 ^ 0x1BD11BDAu;
  x0 += ks0; x1 += ks1;
#define TF_R(r) { x0 += x1; x1 = rotl32(x1, r); x1 ^= x0; }
  TF_R(13u) TF_R(15u) TF_R(26u) TF_R(6u)
  x0 += ks1; x1 += ks2 + 1u;
  TF_R(17u) TF_R(29u) TF_R(16u) TF_R(24u)
  x0 += ks2; x1 += ks0 + 2u;
  TF_R(13u) TF_R(15u) TF_R(26u) TF_R(6u)
  x0 += ks0; x1 += ks1 + 3u;
  TF_R(17u) TF_R(29u) TF_R(16u) TF_R(24u)
  x0 += ks1; x1 += ks2 + 4u;
  TF_R(13u) TF_R(15u) TF_R(26u) TF_R(6u)
  x0 += ks2; x1 += ks0 + 5u;
#undef TF_R
  *o0 = x0; *o1 = x1;
}

__device__ __forceinline__ uint32_t rbits32(uint32_t k0, uint32_t k1,
                                            uint32_t e) {
  uint32_t a, b;
  threefry2x32(k0, k1, 0u, e, &a, &b);
  return a ^ b;
}

__device__ __forceinline__ float gumbel_from_u32(uint32_t bits) {
  uint32_t fb = (bits >> 9) | 0x3f800000u;
  float f = __uint_as_float(fb) - 1.0f;          // [0,1), exact
  float u = (f > 0.0f) ? f : 1.17549435e-38f;    // JAX uniform(minval=tiny)
  float l1 = (float)log((double)u);              // correctly-rounded f32 log
  float l2 = (float)log((double)(-l1));
  return -l2;
}

// -------- operator selection for BOTH layers in one launch --------
__global__ __launch_bounds__(256) void ops_kernel(
    const float* __restrict__ otcA, int nA, uint32_t a0, uint32_t a1,
    int* __restrict__ oA,
    const float* __restrict__ otcB, int nB, uint32_t b0, uint32_t b1,
    int* __restrict__ oB) {
  int t = blockIdx.x * 256 + threadIdx.x;
  const float* otc; int* dst; uint32_t k0, k1; int o;
  if (t < nA) { otc = otcA; dst = oA; k0 = a0; k1 = a1; o = t; }
  else if (t < nA + nB) { otc = otcB; dst = oB; k0 = b0; k1 = b1; o = t - nA; }
  else return;
  float v0 = otc[2 * o] + gumbel_from_u32(rbits32(k0, k1, (uint32_t)(2 * o)));
  float v1 = otc[2 * o + 1] +
             gumbel_from_u32(rbits32(k0, k1, (uint32_t)(2 * o + 1)));
  dst[o] = (v1 > v0) ? 1 : 0;     // argmax, first index wins ties
}

// -------- edge selection for BOTH layers in one launch --------
// layer A: 512 x 1024 (inlog=10), layer B: 1024 x 512 (inlog=9)
__global__ __launch_bounds__(256) void edges_kernel(
    const float* __restrict__ etcA, const int* __restrict__ opA,
    unsigned long long* __restrict__ selA, uint32_t a0, uint32_t a1,
    const float* __restrict__ etcB, const int* __restrict__ opB,
    unsigned long long* __restrict__ selB, uint32_t b0, uint32_t b1) {
  int gid = blockIdx.x * 256 + threadIdx.x;
  const float* etc; const int* opidx; unsigned long long* selw;
  uint32_t k0, k1; int inlog;
  if (gid < 512 * 1024) {
    etc = etcA; opidx = opA; selw = selA; k0 = a0; k1 = a1; inlog = 10;
  } else {
    gid -= 512 * 1024;
    etc = etcB; opidx = opB; selw = selB; k0 = b0; k1 = b1; inlog = 9;
  }
  int o = gid >> inlog;
  int i = gid & ((1 << inlog) - 1);
  int j = opidx[o];
  uint32_t e0 = (uint32_t)((((o * 2 + j) << inlog) + i) * 2);
  float g0 = gumbel_from_u32(rbits32(k0, k1, e0));
  float g1 = gumbel_from_u32(rbits32(k0, k1, e0 + 1u));
  const float* c = etc + (size_t)e0;              // etc flat idx == e0
  bool sel = (c[1] + g1) > (c[0] + g0);
  unsigned long long m = __ballot(sel ? 1 : 0);
  if ((threadIdx.x & 63) == 0) selw[gid >> 6] = m;
}

// -------- layer forward: one wave per (b, 4 consecutive o) --------
// Sign trick: min(v) = -max(-v). op=0(min): s=-1, neutral=-1, negate at end.
//             op=1(max): s=+1, neutral= 0.
template <int IN_F, int OUT_F>
__global__ __launch_bounds__(256) void forward_kernel(
    const float* __restrict__ x, const int* __restrict__ opidx,
    const unsigned long long* __restrict__ selw, float* __restrict__ out) {
  constexpr int W = IN_F / 64;                // u64 mask words per o
  constexpr int CH = IN_F / 256;              // chunks of 256 floats
  int wave = blockIdx.x * 4 + (threadIdx.x >> 6);
  int lane = threadIdx.x & 63;
  int og = wave % (OUT_F / 4);
  int b  = wave / (OUT_F / 4);
  int o0 = og * 4;

  float sgn[4], neu[4];
  int opv[4];
#pragma unroll
  for (int j = 0; j < 4; ++j) {
    int op = opidx[o0 + j];
    opv[j] = op;
    sgn[j] = op ? 1.0f : -1.0f;
    neu[j] = op ? 0.0f : -1.0f;
  }
  float acc[4] = {-1e30f, -1e30f, -1e30f, -1e30f};
  const float* xrow = x + (size_t)b * IN_F;
#pragma unroll
  for (int c = 0; c < CH; ++c) {
    int i0 = c * 256 + lane * 4;
    float4 xv = *(const float4*)(xrow + i0);
    int word = i0 >> 6;
    int bit  = i0 & 63;
#pragma unroll
    for (int j = 0; j < 4; ++j) {
      unsigned long long m = selw[(size_t)(o0 + j) * W + word];
      unsigned int b4 = (unsigned int)(m >> bit) & 0xFu;
      float s = sgn[j], n = neu[j];
      float v0 = (b4 & 1u) ? s * xv.x : n;
      float v1 = (b4 & 2u) ? s * xv.y : n;
      float v2 = (b4 & 4u) ? s * xv.z : n;
      float v3 = (b4 & 8u) ? s * xv.w : n;
      acc[j] = fmaxf(acc[j], fmaxf(fmaxf(v0, v1), fmaxf(v2, v3)));
    }
  }
#pragma unroll
  for (int d = 1; d < 64; d <<= 1) {
#pragma unroll
    for (int j = 0; j < 4; ++j)
      acc[j] = fmaxf(acc[j], __shfl_xor(acc[j], d, 64));
  }
  if (lane == 0) {
    float4 r;
    r.x = opv[0] ? acc[0] : -acc[0];
    r.y = opv[1] ? acc[1] : -acc[1];
    r.z = opv[2] ? acc[2] : -acc[2];
    r.w = opv[3] ? acc[3] : -acc[3];
    *(float4*)(out + (size_t)b * OUT_F + o0) = r;
  }
}

extern "C" void kernel_launch(void* const* d_in, const int* in_sizes, int n_in,
                              void* d_out, int out_size, void* d_ws, size_t ws_size,
                              hipStream_t stream) {
  const float* x    = (const float*)d_in[0];   // [128,1024]
  const float* etc0 = (const float*)d_in[1];   // [512,2,1024,2]
  const float* otc0 = (const float*)d_in[2];   // [512,2]
  const float* etc1 = (const float*)d_in[3];   // [1024,2,512,2]
  const float* otc1 = (const float*)d_in[4];   // [1024,2]
  float* out = (float*)d_out;                  // [128,1024] f32

  // ---- host-side key derivation (pure CPU, graph-capture safe) ----
  uint32_t K0a, K0b, K1a, K1b;
  threefry2x32(0u, 42u, 0u, 0u, &K0a, &K0b);   // fold_in(key(42), 0)
  threefry2x32(0u, 42u, 0u, 1u, &K1a, &K1b);   // fold_in(key(42), 1)
  uint32_t op0k0, op0k1, ed0k0, ed0k1;
  threefry2x32(K0a, K0b, 0u, 0u, &op0k0, &op0k1);
  threefry2x32(K0a, K0b, 0u, 1u, &ed0k0, &ed0k1);
  uint32_t op1k0, op1k1, ed1k0, ed1k1;
  threefry2x32(K1a, K1b, 0u, 0u, &op1k0, &op1k1);
  threefry2x32(K1a, K1b, 0u, 1u, &ed1k0, &ed1k1);

  // ---- workspace layout ----
  char* wsb = (char*)d_ws;
  int* opidx0 = (int*)wsb;                                        // 512 ints
  int* opidx1 = (int*)(wsb + 2048);                               // 1024 ints
  unsigned long long* selw0 = (unsigned long long*)(wsb + 8192);  // 512*16 u64
  unsigned long long* selw1 = (unsigned long long*)(wsb + 8192 + 65536); // 1024*8
  float* h = (float*)(wsb + 8192 + 131072);                       // 128*512 f32

  hipLaunchKernelGGL(ops_kernel, dim3(6), dim3(256), 0, stream,
                     otc0, 512, op0k0, op0k1, opidx0,
                     otc1, 1024, op1k0, op1k1, opidx1);
  hipLaunchKernelGGL(edges_kernel, dim3(4096), dim3(256), 0, stream,
                     etc0, opidx0, selw0, ed0k0, ed0k1,
                     etc1, opidx1, selw1, ed1k0, ed1k1);
  hipLaunchKernelGGL((forward_kernel<1024, 512>), dim3(4096), dim3(256), 0,
                     stream, x, opidx0, selw0, h);
  hipLaunchKernelGGL((forward_kernel<512, 1024>), dim3(8192), dim3(256), 0,
                     stream, h, opidx1, selw1, out);
}

// Round 4
// 114.103 us; speedup vs baseline: 1.4532x; 1.0362x over previous
//
#include <hip/hip_runtime.h>
#include <stdint.h>

// FFEdgeCountingAutoencoder4: two "fuzzy logic" layers.
// Randomness: JAX threefry2x32, PARTITIONABLE counter semantics:
//   bits(e) = o0 ^ o1 of threefry(key, (0, e)).   (verified: absmax == 0.0)
// Keys host-side: base=key(42)=(0,42); K_l=tf(base,(0,l));
//   split: k_op=tf(K,(0,0)), k_edge=tf(K,(0,1)).
// Gumbel: u = max(tiny, ((bits>>9)|0x3f800000 as float)-1); g=-log(-log u),
// each f32 log emulated by an f64 log rounded to f32 (bit-exact vs ref,
// validated rounds 2-3). f64 log is a branch-free inline (atanh series),
// ~2-ulp f64 accurate -> same f32 rounding as libm with prob ~1-2e-8/draw.

__host__ __device__ inline uint32_t rotl32(uint32_t x, uint32_t d) {
  return (x << d) | (x >> (32u - d));
}

__host__ __device__ inline void threefry2x32(uint32_t k0, uint32_t k1,
                                             uint32_t x0, uint32_t x1,
                                             uint32_t* o0, uint32_t* o1) {
  uint32_t ks0 = k0, ks1 = k1, ks2 = k0 ^ k1 ^ 0x1BD11BDAu;
  x0 += ks0; x1 += ks1;
#define TF_R(r) { x0 += x1; x1 = rotl32(x1, r); x1 ^= x0; }
  TF_R(13u) TF_R(15u) TF_R(26u) TF_R(6u)
  x0 += ks1; x1 += ks2 + 1u;
  TF_R(17u) TF_R(29u) TF_R(16u) TF_R(24u)
  x0 += ks2; x1 += ks0 + 2u;
  TF_R(13u) TF_R(15u) TF_R(26u) TF_R(6u)
  x0 += ks0; x1 += ks1 + 3u;
  TF_R(17u) TF_R(29u) TF_R(16u) TF_R(24u)
  x0 += ks1; x1 += ks2 + 4u;
  TF_R(13u) TF_R(15u) TF_R(26u) TF_R(6u)
  x0 += ks2; x1 += ks0 + 5u;
#undef TF_R
  *o0 = x0; *o1 = x1;
}

__device__ __forceinline__ uint32_t rbits32(uint32_t k0, uint32_t k1,
                                            uint32_t e) {
  uint32_t a, b;
  threefry2x32(k0, k1, 0u, e, &a, &b);
  return a ^ b;
}

// Branch-free f64 log for normal positive finite x (our domain:
// u in [1.17e-38, 1), -l1 in [5.9e-8, 88]). ~2 ulp f64.
__device__ __forceinline__ double flog(double x) {
  long long bits = __double_as_longlong(x);
  int e = (int)(bits >> 52) - 1023;
  double m = __longlong_as_double((bits & 0x000fffffffffffffLL) |
                                  0x3ff0000000000000LL);   // [1,2)
  // normalize to [sqrt2/2, sqrt2) so e==0 when x near 1 (no cancellation)
  if (m > 1.4142135623730951) { m *= 0.5; e += 1; }
  double z = (m - 1.0) / (m + 1.0);      // |z| <= 0.1716
  double w = z * z;                      // <= 0.02944
  double p = 1.0 / 19.0;
  p = __builtin_fma(p, w, 1.0 / 17.0);
  p = __builtin_fma(p, w, 1.0 / 15.0);
  p = __builtin_fma(p, w, 1.0 / 13.0);
  p = __builtin_fma(p, w, 1.0 / 11.0);
  p = __builtin_fma(p, w, 1.0 / 9.0);
  p = __builtin_fma(p, w, 1.0 / 7.0);
  p = __builtin_fma(p, w, 1.0 / 5.0);
  p = __builtin_fma(p, w, 1.0 / 3.0);
  p = __builtin_fma(p, w, 1.0);
  double de = (double)e;
  const double ln2_hi = 6.93147180369123816490e-01;  // low bits zero
  const double ln2_lo = 1.90821492927058770002e-10;
  return __builtin_fma(de, ln2_hi,
                       __builtin_fma(2.0 * z, p, de * ln2_lo));
}

__device__ __forceinline__ float gumbel_from_u32(uint32_t bits) {
  uint32_t fb = (bits >> 9) | 0x3f800000u;
  float f = __uint_as_float(fb) - 1.0f;          // [0,1), exact
  float u = (f > 0.0f) ? f : 1.17549435e-38f;    // JAX uniform(minval=tiny)
  float l1 = (float)flog((double)u);
  float l2 = (float)flog((double)(-l1));
  return -l2;
}

// -------- edge selection for BOTH layers (+ fused op selection) --------
// Each 256-thread block covers i-range of exactly one o. Lanes 0,1 of each
// wave compute the two op-gumbels for that o, shfl-broadcast the argmax,
// and thread 0 of the block stores opidx[o] (redundant same-value stores ok).
__global__ __launch_bounds__(256) void edges_kernel(
    const float* __restrict__ etcA, const float* __restrict__ otcA,
    uint32_t oa0, uint32_t oa1, uint32_t ea0, uint32_t ea1,
    int* __restrict__ opA, unsigned long long* __restrict__ selA,
    const float* __restrict__ etcB, const float* __restrict__ otcB,
    uint32_t ob0, uint32_t ob1, uint32_t eb0, uint32_t eb1,
    int* __restrict__ opB, unsigned long long* __restrict__ selB) {
  int gid = blockIdx.x * 256 + threadIdx.x;
  const float *etc, *otc; unsigned long long* selw; int* opx;
  uint32_t ok0, ok1, k0, k1; int inlog;
  if (gid < 512 * 1024) {
    etc = etcA; otc = otcA; opx = opA; selw = selA;
    ok0 = oa0; ok1 = oa1; k0 = ea0; k1 = ea1; inlog = 10;
  } else {
    gid -= 512 * 1024;
    etc = etcB; otc = otcB; opx = opB; selw = selB;
    ok0 = ob0; ok1 = ob1; k0 = eb0; k1 = eb1; inlog = 9;
  }
  int o = gid >> inlog;
  int lane = threadIdx.x & 63;
  float v = 0.0f;
  if (lane < 2)
    v = otc[2 * o + lane] +
        gumbel_from_u32(rbits32(ok0, ok1, (uint32_t)(2 * o + lane)));
  int j = (__shfl(v, 1, 64) > __shfl(v, 0, 64)) ? 1 : 0;  // argmax, tie->0
  if (threadIdx.x == 0) opx[o] = j;
  int i = gid & ((1 << inlog) - 1);
  uint32_t e0 = (uint32_t)((((o * 2 + j) << inlog) + i) * 2);
  float g0 = gumbel_from_u32(rbits32(k0, k1, e0));
  float g1 = gumbel_from_u32(rbits32(k0, k1, e0 + 1u));
  const float* c = etc + (size_t)e0;              // etc flat idx == e0
  bool sel = (c[1] + g1) > (c[0] + g0);
  unsigned long long m = __ballot(sel ? 1 : 0);
  if (lane == 0) selw[gid >> 6] = m;
}

// -------- layer forward: one wave per (b, 4 consecutive o) --------
// Sign trick: min(v) = -max(-v). op=0(min): s=-1, neutral=-1, negate at end.
template <int IN_F, int OUT_F>
__global__ __launch_bounds__(256) void forward_kernel(
    const float* __restrict__ x, const int* __restrict__ opidx,
    const unsigned long long* __restrict__ selw, float* __restrict__ out) {
  constexpr int W = IN_F / 64;                // u64 mask words per o
  constexpr int CH = IN_F / 256;              // chunks of 256 floats
  int wave = blockIdx.x * 4 + (threadIdx.x >> 6);
  int lane = threadIdx.x & 63;
  int og = wave % (OUT_F / 4);
  int b  = wave / (OUT_F / 4);
  int o0 = og * 4;

  float sgn[4], neu[4];
  int opv[4];
#pragma unroll
  for (int j = 0; j < 4; ++j) {
    int op = opidx[o0 + j];
    opv[j] = op;
    sgn[j] = op ? 1.0f : -1.0f;
    neu[j] = op ? 0.0f : -1.0f;
  }
  float acc[4] = {-1e30f, -1e30f, -1e30f, -1e30f};
  const float* xrow = x + (size_t)b * IN_F;
#pragma unroll
  for (int c = 0; c < CH; ++c) {
    int i0 = c * 256 + lane * 4;
    float4 xv = *(const float4*)(xrow + i0);
    int word = i0 >> 6;
    int bit  = i0 & 63;
#pragma unroll
    for (int j = 0; j < 4; ++j) {
      unsigned long long m = selw[(size_t)(o0 + j) * W + word];
      unsigned int b4 = (unsigned int)(m >> bit) & 0xFu;
      float s = sgn[j], n = neu[j];
      float v0 = (b4 & 1u) ? s * xv.x : n;
      float v1 = (b4 & 2u) ? s * xv.y : n;
      float v2 = (b4 & 4u) ? s * xv.z : n;
      float v3 = (b4 & 8u) ? s * xv.w : n;
      acc[j] = fmaxf(acc[j], fmaxf(fmaxf(v0, v1), fmaxf(v2, v3)));
    }
  }
#pragma unroll
  for (int d = 1; d < 64; d <<= 1) {
#pragma unroll
    for (int j = 0; j < 4; ++j)
      acc[j] = fmaxf(acc[j], __shfl_xor(acc[j], d, 64));
  }
  if (lane == 0) {
    float4 r;
    r.x = opv[0] ? acc[0] : -acc[0];
    r.y = opv[1] ? acc[1] : -acc[1];
    r.z = opv[2] ? acc[2] : -acc[2];
    r.w = opv[3] ? acc[3] : -acc[3];
    *(float4*)(out + (size_t)b * OUT_F + o0) = r;
  }
}

extern "C" void kernel_launch(void* const* d_in, const int* in_sizes, int n_in,
                              void* d_out, int out_size, void* d_ws, size_t ws_size,
                              hipStream_t stream) {
  const float* x    = (const float*)d_in[0];   // [128,1024]
  const float* etc0 = (const float*)d_in[1];   // [512,2,1024,2]
  const float* otc0 = (const float*)d_in[2];   // [512,2]
  const float* etc1 = (const float*)d_in[3];   // [1024,2,512,2]
  const float* otc1 = (const float*)d_in[4];   // [1024,2]
  float* out = (float*)d_out;                  // [128,1024] f32

  // ---- host-side key derivation (pure CPU, graph-capture safe) ----
  uint32_t K0a, K0b, K1a, K1b;
  threefry2x32(0u, 42u, 0u, 0u, &K0a, &K0b);   // fold_in(key(42), 0)
  threefry2x32(0u, 42u, 0u, 1u, &K1a, &K1b);   // fold_in(key(42), 1)
  uint32_t op0k0, op0k1, ed0k0, ed0k1;
  threefry2x32(K0a, K0b, 0u, 0u, &op0k0, &op0k1);
  threefry2x32(K0a, K0b, 0u, 1u, &ed0k0, &ed0k1);
  uint32_t op1k0, op1k1, ed1k0, ed1k1;
  threefry2x32(K1a, K1b, 0u, 0u, &op1k0, &op1k1);
  threefry2x32(K1a, K1b, 0u, 1u, &ed1k0, &ed1k1);

  // ---- workspace layout ----
  char* wsb = (char*)d_ws;
  int* opidx0 = (int*)wsb;                                        // 512 ints
  int* opidx1 = (int*)(wsb + 2048);                               // 1024 ints
  unsigned long long* selw0 = (unsigned long long*)(wsb + 8192);  // 512*16 u64
  unsigned long long* selw1 = (unsigned long long*)(wsb + 8192 + 65536); // 1024*8
  float* h = (float*)(wsb + 8192 + 131072);                       // 128*512 f32

  hipLaunchKernelGGL(edges_kernel, dim3(4096), dim3(256), 0, stream,
                     etc0, otc0, op0k0, op0k1, ed0k0, ed0k1, opidx0, selw0,
                     etc1, otc1, op1k0, op1k1, ed1k0, ed1k1, opidx1, selw1);
  hipLaunchKernelGGL((forward_kernel<1024, 512>), dim3(4096), dim3(256), 0,
                     stream, x, opidx0, selw0, h);
  hipLaunchKernelGGL((forward_kernel<512, 1024>), dim3(8192), dim3(256), 0,
                     stream, h, opidx1, selw1, out);
}

// Round 5
// 113.808 us; speedup vs baseline: 1.4570x; 1.0026x over previous
//
#include <hip/hip_runtime.h>
#include <stdint.h>

// FFEdgeCountingAutoencoder4: two "fuzzy logic" layers.
// Randomness: JAX threefry2x32, PARTITIONABLE counter semantics:
//   bits(e) = o0 ^ o1 of threefry(key, (0, e)).   (verified: absmax == 0.0)
// Keys host-side: base=key(42)=(0,42); K_l=tf(base,(0,l));
//   split: k_op=tf(K,(0,0)), k_edge=tf(K,(0,1)).
// Gumbel: u = max(tiny, ((bits>>9)|0x3f800000 as float)-1); g=-log(-log u),
// each f32 log emulated by an f64 log rounded to f32 (bit-exact vs ref,
// validated rounds 2-4). flog: branch-light atanh-series, rcp_f64+2NR
// instead of exact div (rel err ~1e-15, f32-rounding-safe).

__host__ __device__ inline uint32_t rotl32(uint32_t x, uint32_t d) {
  return (x << d) | (x >> (32u - d));
}

__host__ __device__ inline void threefry2x32(uint32_t k0, uint32_t k1,
                                             uint32_t x0, uint32_t x1,
                                             uint32_t* o0, uint32_t* o1) {
  uint32_t ks0 = k0, ks1 = k1, ks2 = k0 ^ k1 ^ 0x1BD11BDAu;
  x0 += ks0; x1 += ks1;
#define TF_R(r) { x0 += x1; x1 = rotl32(x1, r); x1 ^= x0; }
  TF_R(13u) TF_R(15u) TF_R(26u) TF_R(6u)
  x0 += ks1; x1 += ks2 + 1u;
  TF_R(17u) TF_R(29u) TF_R(16u) TF_R(24u)
  x0 += ks2; x1 += ks0 + 2u;
  TF_R(13u) TF_R(15u) TF_R(26u) TF_R(6u)
  x0 += ks0; x1 += ks1 + 3u;
  TF_R(17u) TF_R(29u) TF_R(16u) TF_R(24u)
  x0 += ks1; x1 += ks2 + 4u;
  TF_R(13u) TF_R(15u) TF_R(26u) TF_R(6u)
  x0 += ks2; x1 += ks0 + 5u;
#undef TF_R
  *o0 = x0; *o1 = x1;
}

__device__ __forceinline__ uint32_t rbits32(uint32_t k0, uint32_t k1,
                                            uint32_t e) {
  uint32_t a, b;
  threefry2x32(k0, k1, 0u, e, &a, &b);
  return a ^ b;
}

// f64 log for normal positive finite x (domain: u in [1.17e-38,1),
// -l1 in [5.9e-8, 88.8]). rel err ~1e-12 — far inside the f32-rounding
// safety margin (boundary-crossing prob < 1e-4 over all 4.2M draws).
__device__ __forceinline__ double flog(double x) {
  long long bits = __double_as_longlong(x);
  int e = (int)(bits >> 52) - 1023;
  double m = __longlong_as_double((bits & 0x000fffffffffffffLL) |
                                  0x3ff0000000000000LL);   // [1,2)
  // normalize to [sqrt2/2, sqrt2) so e==0 when x near 1 (no cancellation)
  if (m > 1.4142135623730951) { m *= 0.5; e += 1; }
  double mp1 = m + 1.0;
  double r = __builtin_amdgcn_rcp(mp1);            // v_rcp_f64, ~2^-29
  r = r * __builtin_fma(-mp1, r, 2.0);             // NR1
  r = r * __builtin_fma(-mp1, r, 2.0);             // NR2 -> ~1 ulp f64
  double z = (m - 1.0) * r;              // |z| <= 0.1716
  double w = z * z;                      // <= 0.02944
  double p = 1.0 / 15.0;
  p = __builtin_fma(p, w, 1.0 / 13.0);
  p = __builtin_fma(p, w, 1.0 / 11.0);
  p = __builtin_fma(p, w, 1.0 / 9.0);
  p = __builtin_fma(p, w, 1.0 / 7.0);
  p = __builtin_fma(p, w, 1.0 / 5.0);
  p = __builtin_fma(p, w, 1.0 / 3.0);
  p = __builtin_fma(p, w, 1.0);
  double de = (double)e;
  const double ln2_hi = 6.93147180369123816490e-01;  // low bits zero
  const double ln2_lo = 1.90821492927058770002e-10;
  return __builtin_fma(de, ln2_hi,
                       __builtin_fma(2.0 * z, p, de * ln2_lo));
}

__device__ __forceinline__ float gumbel_from_u32(uint32_t bits) {
  uint32_t fb = (bits >> 9) | 0x3f800000u;
  float f = __uint_as_float(fb) - 1.0f;          // [0,1), exact
  float u = (f > 0.0f) ? f : 1.17549435e-38f;    // JAX uniform(minval=tiny)
  float l1 = (float)flog((double)u);
  float l2 = (float)flog((double)(-l1));
  return -l2;
}

// -------- edge selection for BOTH layers (+ fused op selection) --------
// Each 256-thread block covers i-range of exactly one o. Lanes 0,1 of each
// wave compute the two op-gumbels for that o, shfl-broadcast the argmax,
// and thread 0 of the block stores opidx[o] (redundant same-value stores ok).
__global__ __launch_bounds__(256) void edges_kernel(
    const float* __restrict__ etcA, const float* __restrict__ otcA,
    uint32_t oa0, uint32_t oa1, uint32_t ea0, uint32_t ea1,
    int* __restrict__ opA, unsigned long long* __restrict__ selA,
    const float* __restrict__ etcB, const float* __restrict__ otcB,
    uint32_t ob0, uint32_t ob1, uint32_t eb0, uint32_t eb1,
    int* __restrict__ opB, unsigned long long* __restrict__ selB) {
  int gid = blockIdx.x * 256 + threadIdx.x;
  const float *etc, *otc; unsigned long long* selw; int* opx;
  uint32_t ok0, ok1, k0, k1; int inlog;
  if (gid < 512 * 1024) {
    etc = etcA; otc = otcA; opx = opA; selw = selA;
    ok0 = oa0; ok1 = oa1; k0 = ea0; k1 = ea1; inlog = 10;
  } else {
    gid -= 512 * 1024;
    etc = etcB; otc = otcB; opx = opB; selw = selB;
    ok0 = ob0; ok1 = ob1; k0 = eb0; k1 = eb1; inlog = 9;
  }
  int o = gid >> inlog;
  int lane = threadIdx.x & 63;
  float v = 0.0f;
  if (lane < 2)
    v = otc[2 * o + lane] +
        gumbel_from_u32(rbits32(ok0, ok1, (uint32_t)(2 * o + lane)));
  int j = (__shfl(v, 1, 64) > __shfl(v, 0, 64)) ? 1 : 0;  // argmax, tie->0
  if (threadIdx.x == 0) opx[o] = j;
  int i = gid & ((1 << inlog) - 1);
  uint32_t e0 = (uint32_t)((((o * 2 + j) << inlog) + i) * 2);
  float g0 = gumbel_from_u32(rbits32(k0, k1, e0));
  float g1 = gumbel_from_u32(rbits32(k0, k1, e0 + 1u));
  const float* c = etc + (size_t)e0;              // etc flat idx == e0
  bool sel = (c[1] + g1) > (c[0] + g0);
  unsigned long long m = __ballot(sel ? 1 : 0);
  if (lane == 0) selw[gid >> 6] = m;
}

// -------- layer forward: one wave per (b, 8 consecutive o) --------
// Sign trick: min(v) = -max(-v). op=0(min): s=-1, neutral=-1, negate at end.
template <int IN_F, int OUT_F>
__global__ __launch_bounds__(256) void forward_kernel(
    const float* __restrict__ x, const int* __restrict__ opidx,
    const unsigned long long* __restrict__ selw, float* __restrict__ out) {
  constexpr int W = IN_F / 64;                // u64 mask words per o
  constexpr int CH = IN_F / 256;              // chunks of 256 floats
  int wave = blockIdx.x * 4 + (threadIdx.x >> 6);
  int lane = threadIdx.x & 63;
  int og = wave % (OUT_F / 8);
  int b  = wave / (OUT_F / 8);
  int o0 = og * 8;

  float sgn[8], neu[8];
  int opv[8];
#pragma unroll
  for (int j = 0; j < 8; ++j) {
    int op = opidx[o0 + j];
    opv[j] = op;
    sgn[j] = op ? 1.0f : -1.0f;
    neu[j] = op ? 0.0f : -1.0f;
  }
  float acc[8];
#pragma unroll
  for (int j = 0; j < 8; ++j) acc[j] = -1e30f;
  const float* xrow = x + (size_t)b * IN_F;
#pragma unroll
  for (int c = 0; c < CH; ++c) {
    int i0 = c * 256 + lane * 4;
    float4 xv = *(const float4*)(xrow + i0);
    int word = i0 >> 6;
    int bit  = i0 & 63;
#pragma unroll
    for (int j = 0; j < 8; ++j) {
      unsigned long long m = selw[(size_t)(o0 + j) * W + word];
      unsigned int b4 = (unsigned int)(m >> bit) & 0xFu;
      float s = sgn[j], n = neu[j];
      float v0 = (b4 & 1u) ? s * xv.x : n;
      float v1 = (b4 & 2u) ? s * xv.y : n;
      float v2 = (b4 & 4u) ? s * xv.z : n;
      float v3 = (b4 & 8u) ? s * xv.w : n;
      acc[j] = fmaxf(acc[j], fmaxf(fmaxf(v0, v1), fmaxf(v2, v3)));
    }
  }
#pragma unroll
  for (int d = 1; d < 64; d <<= 1) {
#pragma unroll
    for (int j = 0; j < 8; ++j)
      acc[j] = fmaxf(acc[j], __shfl_xor(acc[j], d, 64));
  }
  if (lane == 0) {
    float4 r0, r1;
    r0.x = opv[0] ? acc[0] : -acc[0];
    r0.y = opv[1] ? acc[1] : -acc[1];
    r0.z = opv[2] ? acc[2] : -acc[2];
    r0.w = opv[3] ? acc[3] : -acc[3];
    r1.x = opv[4] ? acc[4] : -acc[4];
    r1.y = opv[5] ? acc[5] : -acc[5];
    r1.z = opv[6] ? acc[6] : -acc[6];
    r1.w = opv[7] ? acc[7] : -acc[7];
    float* op = out + (size_t)b * OUT_F + o0;
    *(float4*)op = r0;
    *(float4*)(op + 4) = r1;
  }
}

extern "C" void kernel_launch(void* const* d_in, const int* in_sizes, int n_in,
                              void* d_out, int out_size, void* d_ws, size_t ws_size,
                              hipStream_t stream) {
  const float* x    = (const float*)d_in[0];   // [128,1024]
  const float* etc0 = (const float*)d_in[1];   // [512,2,1024,2]
  const float* otc0 = (const float*)d_in[2];   // [512,2]
  const float* etc1 = (const float*)d_in[3];   // [1024,2,512,2]
  const float* otc1 = (const float*)d_in[4];   // [1024,2]
  float* out = (float*)d_out;                  // [128,1024] f32

  // ---- host-side key derivation (pure CPU, graph-capture safe) ----
  uint32_t K0a, K0b, K1a, K1b;
  threefry2x32(0u, 42u, 0u, 0u, &K0a, &K0b);   // fold_in(key(42), 0)
  threefry2x32(0u, 42u, 0u, 1u, &K1a, &K1b);   // fold_in(key(42), 1)
  uint32_t op0k0, op0k1, ed0k0, ed0k1;
  threefry2x32(K0a, K0b, 0u, 0u, &op0k0, &op0k1);
  threefry2x32(K0a, K0b, 0u, 1u, &ed0k0, &ed0k1);
  uint32_t op1k0, op1k1, ed1k0, ed1k1;
  threefry2x32(K1a, K1b, 0u, 0u, &op1k0, &op1k1);
  threefry2x32(K1a, K1b, 0u, 1u, &ed1k0, &ed1k1);

  // ---- workspace layout ----
  char* wsb = (char*)d_ws;
  int* opidx0 = (int*)wsb;                                        // 512 ints
  int* opidx1 = (int*)(wsb + 2048);                               // 1024 ints
  unsigned long long* selw0 = (unsigned long long*)(wsb + 8192);  // 512*16 u64
  unsigned long long* selw1 = (unsigned long long*)(wsb + 8192 + 65536); // 1024*8
  float* h = (float*)(wsb + 8192 + 131072);                       // 128*512 f32

  hipLaunchKernelGGL(edges_kernel, dim3(4096), dim3(256), 0, stream,
                     etc0, otc0, op0k0, op0k1, ed0k0, ed0k1, opidx0, selw0,
                     etc1, otc1, op1k0, op1k1, ed1k0, ed1k1, opidx1, selw1);
  hipLaunchKernelGGL((forward_kernel<1024, 512>), dim3(2048), dim3(256), 0,
                     stream, x, opidx0, selw0, h);
  hipLaunchKernelGGL((forward_kernel<512, 1024>), dim3(4096), dim3(256), 0,
                     stream, h, opidx1, selw1, out);
}